// Round 4
// baseline (25919.785 us; speedup 1.0000x reference)
//
#include <hip/hip_runtime.h>

#define DEV __device__ __forceinline__
typedef unsigned short us;
typedef __bf16 bf8 __attribute__((ext_vector_type(8)));
typedef float  f4  __attribute__((ext_vector_type(4)));

DEV us f2bf(float f){
  unsigned int u = __builtin_bit_cast(unsigned int, f);
  u = u + 0x7fffu + ((u >> 16) & 1u);
  return (us)(u >> 16);
}
DEV float sigm(float x){ return 1.f/(1.f + __expf(-x)); }
DEV bf8 ldb(const us* p){ return *reinterpret_cast<const bf8*>(p); }
DEV f4 mfma(bf8 a, bf8 b, f4 c){ return __builtin_amdgcn_mfma_f32_16x16x32_bf16(a, b, c, 0, 0, 0); }

// ---------------- workspace layout (bytes) — total ~171 MB
constexpr size_t OFF_WCAT0  = 0;                            // [2][1536][544] bf16
constexpr size_t OFF_WCAT1  = OFF_WCAT0 + 2ull*1536*544*2;  // [1536][1536] bf16
constexpr size_t OFF_W1R    = OFF_WCAT1 + 1536ull*1536*2;   // [1536][1024] bf16
constexpr size_t OFF_FC1W   = OFF_W1R   + 1536ull*1024*2;   // [256][1024] bf16
constexpr size_t OFF_FC2W   = OFF_FC1W  + 256ull*1024*2;    // [16][256] bf16
constexpr size_t OFF_BRZ0   = OFF_FC2W  + 16ull*256*2;      // [2][1024] f32
constexpr size_t OFF_BNIH0  = OFF_BRZ0  + 2*1024*4;         // [2][512]
constexpr size_t OFF_BNHH0  = OFF_BNIH0 + 2*512*4;          // [2][512]
constexpr size_t OFF_BRZ1   = OFF_BNHH0 + 2*512*4;          // [1024]
constexpr size_t OFF_BNIH1  = OFF_BRZ1  + 1024*4;           // [512]
constexpr size_t OFF_BNHH1  = OFF_BNIH1 + 512*4;            // [512]
constexpr size_t OFF_BRZ1R  = OFF_BNHH1 + 512*4;            // [1024]
constexpr size_t OFF_BNIH1R = OFF_BRZ1R + 1024*4;           // [512]
constexpr size_t OFF_BNHH1R = OFF_BNIH1R+ 512*4;            // [512]
constexpr size_t OFF_SC2    = OFF_BNHH1R+ 512*4;            // [256]
constexpr size_t OFF_SH2    = OFF_SC2   + 256*4;            // [256]
constexpr size_t OFF_FC2B   = OFF_SH2   + 256*4;            // [16]
constexpr size_t OFF_Y0B    = OFF_FC2B  + 64;               // [4096][28][512] bf16
constexpr size_t OFF_H0BF   = OFF_Y0B   + 4096ull*28*512*2; // [2pp][4096][512] bf16
constexpr size_t OFF_H0F32  = OFF_H0BF  + 2ull*4096*512*2;  // [4096][512] f32
constexpr size_t OFF_H1BF   = OFF_H0F32 + 4096ull*512*4;    // [2pp][4096][512] bf16
constexpr size_t OFF_H1F32  = OFF_H1BF  + 2ull*4096*512*2;  // [4096][512] f32
constexpr size_t OFF_H1BBF  = OFF_H1F32 + 4096ull*512*4;    // [4096][512] bf16

constexpr long PP = 4096ll*512;

// ---------------- K0: weight/bias prep ----------------
__global__ void prep_kernel(
  const float* __restrict__ Wih0, const float* __restrict__ Whh0,
  const float* __restrict__ bih0, const float* __restrict__ bhh0,
  const float* __restrict__ Wih0r,const float* __restrict__ Whh0r,
  const float* __restrict__ bih0r,const float* __restrict__ bhh0r,
  const float* __restrict__ Wih1, const float* __restrict__ Whh1,
  const float* __restrict__ bih1, const float* __restrict__ bhh1,
  const float* __restrict__ Wih1r,const float* __restrict__ bih1r,
  const float* __restrict__ bhh1r,
  const float* __restrict__ fc1w, const float* __restrict__ fc1b,
  const float* __restrict__ gma,  const float* __restrict__ bta,
  const float* __restrict__ mean, const float* __restrict__ var,
  const float* __restrict__ fc2w, const float* __restrict__ fc2b,
  us* __restrict__ wcat0, us* __restrict__ wcat1, us* __restrict__ w1r,
  us* __restrict__ fc1wb, us* __restrict__ fc2wp,
  float* __restrict__ brz0, float* __restrict__ bnih0, float* __restrict__ bnhh0,
  float* __restrict__ brz1, float* __restrict__ bnih1, float* __restrict__ bnhh1,
  float* __restrict__ brz1r,float* __restrict__ bnih1r,float* __restrict__ bnhh1r,
  float* __restrict__ sc2,  float* __restrict__ sh2,   float* __restrict__ fc2bp)
{
  const int tid = blockIdx.x * blockDim.x + threadIdx.x;
  const int np  = gridDim.x * blockDim.x;
  for (int i = tid; i < 2*1536*544; i += np){
    int d = i / (1536*544); int rem = i - d*(1536*544);
    int n = rem / 544, k = rem - n*544;
    const float* ih = d ? Wih0r : Wih0;
    const float* hh = d ? Whh0r : Whh0;
    float v = (k < 32) ? (k < 28 ? ih[n*28 + k] : 0.f) : hh[n*512 + (k-32)];
    wcat0[i] = f2bf(v);
  }
  for (int i = tid; i < 1536*1536; i += np){
    int n = i / 1536, k = i - n*1536;
    float v = (k < 1024) ? Wih1[n*1024 + k] : Whh1[n*512 + (k-1024)];
    wcat1[i] = f2bf(v);
  }
  for (int i = tid; i < 1536*1024; i += np) w1r[i]   = f2bf(Wih1r[i]);
  for (int i = tid; i < 256*1024;  i += np) fc1wb[i] = f2bf(fc1w[i]);
  for (int i = tid; i < 16*256;    i += np){
    int n = i / 256; fc2wp[i] = (n < 10) ? f2bf(fc2w[i]) : (us)0;
  }
  for (int i = tid; i < 1024; i += np){
    brz0[i]        = bih0[i]  + bhh0[i];
    brz0[1024 + i] = bih0r[i] + bhh0r[i];
    brz1[i]        = bih1[i]  + bhh1[i];
    brz1r[i]       = bih1r[i] + bhh1r[i];
  }
  for (int i = tid; i < 512; i += np){
    bnih0[i]       = bih0[1024 + i];   bnhh0[i]       = bhh0[1024 + i];
    bnih0[512 + i] = bih0r[1024 + i];  bnhh0[512 + i] = bhh0r[1024 + i];
    bnih1[i]       = bih1[1024 + i];   bnhh1[i]       = bhh1[1024 + i];
    bnih1r[i]      = bih1r[1024 + i];  bnhh1r[i]      = bhh1r[1024 + i];
  }
  for (int i = tid; i < 256; i += np){
    float s = gma[i] * rsqrtf(var[i] + 1e-5f);
    sc2[i] = s;
    sh2[i] = (fc1b[i] - mean[i]) * s + bta[i];
  }
  for (int i = tid; i < 16; i += np) fc2bp[i] = (i < 10) ? fc2b[i] : 0.f;
}

// ---------------- generic GRU step ----------------
// One recurrent step as a 2D-tiled GEMM + gate epilogue.
// grid 512: nm = bid&31 (M tile of 128), hcb = bid>>5 (32 h-cols, 16 tiles).
// 8 waves: wm = w>>1 (32 M rows), wn = w&1 (16 hc).
// A = [seg0 (K0) | seg1 (K1) | h], K = nk*32; seg0 = fp32 x if xf32.
// n-gate: XN = sum of chunks < kxn (moved to accXN regs at boundary), HN after.
// Pipeline: LDS A triple-buffered; A-loads issued 4 chunks ahead (2-iter slack
// before ds_write), B-frags register-prefetched 2 chunks ahead.
__global__ __launch_bounds__(512, 4) void gru_step_kernel(
  const float* __restrict__ xf32, long xstride,
  const us* __restrict__ src0, long s0stride, int K0,
  const us* __restrict__ src1, long s1stride, int K1,
  const us* __restrict__ hIn, float* __restrict__ hF, us* __restrict__ hOut,
  us* __restrict__ y, long ystride,
  const us* __restrict__ W, int Kw, int nk, int kxn, int first,
  const float* __restrict__ brz, const float* __restrict__ bni,
  const float* __restrict__ bnh)
{
  __shared__ us As[3*128*40];   // 3 bufs of [128 rows][32 cols pad->40]

  const int tid = threadIdx.x, bid = blockIdx.x;
  const int nm = bid & 31, hcb = bid >> 5;
  const size_t Mbase = (size_t)nm * 128;
  const int hcBase = hcb * 32;
  const int K01 = K0 + K1;

  const int w = tid >> 6, lane = tid & 63, ln = lane & 15, lq = lane >> 4;
  const int wm = w >> 1, wn = w & 1;
  const int srow = tid >> 2, sgrp = tid & 3;
  const size_t mrow = Mbase + srow;

  const us* pB0 = W + (size_t)(       hcBase + wn*16 + ln) * Kw + lq*8;
  const us* pB1 = W + (size_t)( 512 + hcBase + wn*16 + ln) * Kw + lq*8;
  const us* pB2 = W + (size_t)(1024 + hcBase + wn*16 + ln) * Kw + lq*8;

  auto loadA = [&](int c) -> uint4 {
    const int col = c*32 + sgrp*8;
    if (col < K0){
      if (xf32){
        const float* xr = xf32 + mrow*xstride;
        us t8[8];
        #pragma unroll
        for (int j = 0; j < 8; ++j){
          int cc = col + j;
          t8[j] = (cc < 28) ? f2bf(xr[cc]) : (us)0;
        }
        return *reinterpret_cast<uint4*>(t8);
      }
      return *reinterpret_cast<const uint4*>(src0 + mrow*s0stride + col);
    } else if (col < K01){
      return *reinterpret_cast<const uint4*>(src1 + mrow*s1stride + (col - K0));
    } else if (!first){
      return *reinterpret_cast<const uint4*>(hIn + mrow*512 + (col - K01));
    }
    return uint4{0,0,0,0};
  };
  auto stA = [&](int b3, uint4 v){
    *reinterpret_cast<uint4*>(&As[b3*5120 + srow*40 + sgrp*8]) = v;
  };

  // ---- prologue: chunks 0,1 -> LDS; 2,3 -> regs; B 0,1 -> regs (nk >= 4 always)
  uint4 vA[2];
  bf8 bBr[2], bBz[2], bBn[2];
  {
    uint4 a0 = loadA(0), a1 = loadA(1);
    bBr[0] = ldb(pB0);      bBz[0] = ldb(pB1);      bBn[0] = ldb(pB2);
    bBr[1] = ldb(pB0 + 32); bBz[1] = ldb(pB1 + 32); bBn[1] = ldb(pB2 + 32);
    stA(0, a0); stA(1, a1);
    vA[0] = loadA(2); vA[1] = loadA(3);
  }
  __syncthreads();

  f4 accR[2] = {}, accZ[2] = {}, accN[2] = {}, accXN[2] = {};

  for (int kt = 0; kt < nk; ++kt){
    const int b3 = (kt % 3) * 5120;
    const int ps = kt & 1;
    bf8 a0 = ldb(&As[b3 + (wm*32 +  0 + ln)*40 + lq*8]);
    bf8 a1 = ldb(&As[b3 + (wm*32 + 16 + ln)*40 + lq*8]);
    accR[0] = mfma(a0, bBr[ps], accR[0]); accR[1] = mfma(a1, bBr[ps], accR[1]);
    accZ[0] = mfma(a0, bBz[ps], accZ[0]); accZ[1] = mfma(a1, bBz[ps], accZ[1]);
    accN[0] = mfma(a0, bBn[ps], accN[0]); accN[1] = mfma(a1, bBn[ps], accN[1]);
    if (kt + 2 < nk){
      stA((kt + 2) % 3, vA[ps]);                       // load issued 2 iters ago
      vA[ps] = (kt + 4 < nk) ? loadA(kt + 4) : uint4{0,0,0,0};
      const int kc = (kt + 2) * 32;
      bBr[ps] = ldb(pB0 + kc); bBz[ps] = ldb(pB1 + kc); bBn[ps] = ldb(pB2 + kc);
    }
    if (kt == kxn - 1){
      accXN[0] = accN[0]; accXN[1] = accN[1];
      accN[0] = f4{0.f,0.f,0.f,0.f}; accN[1] = f4{0.f,0.f,0.f,0.f};
    }
    __syncthreads();
  }

  // ---- gate epilogue ----
  const int c = hcBase + wn*16 + ln;
  const float br = brz[c], bz = brz[512 + c], bi = bni[c], bh = bnh[c];
  #pragma unroll
  for (int mt = 0; mt < 2; ++mt){
    #pragma unroll
    for (int e = 0; e < 4; ++e){
      const size_t m = Mbase + wm*32 + mt*16 + lq*4 + e;
      float r = sigm(accR[mt][e] + br);
      float z = sigm(accZ[mt][e] + bz);
      float n = tanhf(accXN[mt][e] + bi + r*(accN[mt][e] + bh));
      float hprev = first ? 0.f : hF[m*512 + c];
      float h = (1.f - z)*n + z*hprev;
      hF[m*512 + c] = h;
      us hb = f2bf(h);
      hOut[m*512 + c] = hb;
      if (y) y[m*ystride + c] = hb;
    }
  }
}

// ---------------- head: [h1f|h1b] -> fc1 -> bn/relu -> fc2 -> log_softmax ----
__global__ __launch_bounds__(512) void head_kernel(
  const us* __restrict__ h1f, const us* __restrict__ h1b,
  const us* __restrict__ fc1w, const us* __restrict__ fc2wp,
  const float* __restrict__ sc2, const float* __restrict__ sh2,
  const float* __restrict__ fc2b, float* __restrict__ out)
{
  constexpr int APS = 1048;
  __shared__ us As[32 * APS];
  __shared__ us actS[32 * 264];
  __shared__ float lg[32 * 16];
  const int tid = threadIdx.x;
  const size_t row0 = (size_t)blockIdx.x * 32;
  const int w = tid >> 6, lane = tid & 63, ln = lane & 15, lq = lane >> 4;

  for (int i = tid; i < 32*128; i += 512){
    int r = i >> 7, g = i & 127, col = g*8;
    uint4 v = (col < 512)
      ? *reinterpret_cast<const uint4*>(h1f + (row0 + r)*512 + col)
      : *reinterpret_cast<const uint4*>(h1b + (row0 + r)*512 + (col - 512));
    *reinterpret_cast<uint4*>(&As[r*APS + col]) = v;
  }
  __syncthreads();

  {
    f4 acc[2][2] = {};
    for (int kt = 0; kt < 32; ++kt){
      const int kc = kt*32 + lq*8;
      bf8 a0 = ldb(&As[ln*APS + kc]);
      bf8 a1 = ldb(&As[(16 + ln)*APS + kc]);
      #pragma unroll
      for (int nt = 0; nt < 2; ++nt){
        const int col = w*32 + nt*16 + ln;
        bf8 b = ldb(&fc1w[(size_t)col*1024 + kc]);
        acc[0][nt] = mfma(a0, b, acc[0][nt]);
        acc[1][nt] = mfma(a1, b, acc[1][nt]);
      }
    }
    #pragma unroll
    for (int nt = 0; nt < 2; ++nt){
      const int col = w*32 + nt*16 + ln;
      const float sc = sc2[col], sh = sh2[col];
      #pragma unroll
      for (int mt = 0; mt < 2; ++mt)
        #pragma unroll
        for (int e = 0; e < 4; ++e){
          float v = fmaxf(acc[mt][nt][e]*sc + sh, 0.f);
          actS[(mt*16 + lq*4 + e)*264 + col] = f2bf(v);
        }
    }
    __syncthreads();
  }

  if (w == 0){
    f4 acc[2] = {};
    for (int kt = 0; kt < 8; ++kt){
      const int kc = kt*32 + lq*8;
      bf8 a0 = ldb(&actS[ln*264 + kc]);
      bf8 a1 = ldb(&actS[(16 + ln)*264 + kc]);
      bf8 b  = ldb(&fc2wp[ln*256 + kc]);
      acc[0] = mfma(a0, b, acc[0]);
      acc[1] = mfma(a1, b, acc[1]);
    }
    const float bb = fc2b[ln];
    #pragma unroll
    for (int mt = 0; mt < 2; ++mt)
      #pragma unroll
      for (int e = 0; e < 4; ++e)
        lg[(mt*16 + lq*4 + e)*16 + ln] = acc[mt][e] + bb;
  }
  __syncthreads();
  if (tid < 32){
    const int r = tid;
    float mx = -1e30f;
    for (int cc = 0; cc < 10; ++cc) mx = fmaxf(mx, lg[r*16 + cc]);
    float sum = 0.f;
    for (int cc = 0; cc < 10; ++cc) sum += __expf(lg[r*16 + cc] - mx);
    const float lse = mx + logf(sum);
    for (int cc = 0; cc < 10; ++cc)
      out[(row0 + r)*10 + cc] = lg[r*16 + cc] - lse;
  }
}

// ---------------- launch ----------------
extern "C" void kernel_launch(void* const* d_in, const int* in_sizes, int n_in,
                              void* d_out, int out_size, void* d_ws, size_t ws_size,
                              hipStream_t stream)
{
  (void)in_sizes; (void)n_in; (void)out_size; (void)ws_size;
  char* ws = (char*)d_ws;
  auto US = [&](size_t off){ return (us*)(ws + off); };
  auto FP = [&](size_t off){ return (float*)(ws + off); };

  const float* x      = (const float*)d_in[0];
  const float* Wih0   = (const float*)d_in[1];
  const float* Whh0   = (const float*)d_in[2];
  const float* bih0   = (const float*)d_in[3];
  const float* bhh0   = (const float*)d_in[4];
  const float* Wih0r  = (const float*)d_in[5];
  const float* Whh0r  = (const float*)d_in[6];
  const float* bih0r  = (const float*)d_in[7];
  const float* bhh0r  = (const float*)d_in[8];
  const float* Wih1   = (const float*)d_in[9];
  const float* Whh1   = (const float*)d_in[10];
  const float* bih1   = (const float*)d_in[11];
  const float* bhh1   = (const float*)d_in[12];
  const float* Wih1r  = (const float*)d_in[13];
  // d_in[14] (W_hh_l1r) unused: backward layer-1 runs exactly one step from h=0.
  const float* bih1r  = (const float*)d_in[15];
  const float* bhh1r  = (const float*)d_in[16];
  const float* fc1w   = (const float*)d_in[17];
  const float* fc1b   = (const float*)d_in[18];
  const float* gma    = (const float*)d_in[19];
  const float* bta    = (const float*)d_in[20];
  const float* mean   = (const float*)d_in[21];
  const float* var    = (const float*)d_in[22];
  const float* fc2w   = (const float*)d_in[23];
  const float* fc2b   = (const float*)d_in[24];

  prep_kernel<<<512, 256, 0, stream>>>(
    Wih0, Whh0, bih0, bhh0, Wih0r, Whh0r, bih0r, bhh0r,
    Wih1, Whh1, bih1, bhh1, Wih1r, bih1r, bhh1r,
    fc1w, fc1b, gma, bta, mean, var, fc2w, fc2b,
    US(OFF_WCAT0), US(OFF_WCAT1), US(OFF_W1R), US(OFF_FC1W), US(OFF_FC2W),
    FP(OFF_BRZ0), FP(OFF_BNIH0), FP(OFF_BNHH0),
    FP(OFF_BRZ1), FP(OFF_BNIH1), FP(OFF_BNHH1),
    FP(OFF_BRZ1R), FP(OFF_BNIH1R), FP(OFF_BNHH1R),
    FP(OFF_SC2), FP(OFF_SH2), FP(OFF_FC2B));

  us* y0b  = US(OFF_Y0B);
  us* h0bf = US(OFF_H0BF);
  us* h1bf = US(OFF_H1BF);

  // ---- phase A: layer-0 backward (materialize y0b) ----
  for (int s = 0; s < 28; ++s){
    const int t = 27 - s;
    gru_step_kernel<<<512, 512, 0, stream>>>(
      x + t*28, 784, nullptr, 0, 32, nullptr, 0, 0,
      h0bf + (s & 1)*PP, FP(OFF_H0F32), h0bf + ((s & 1) ^ 1)*PP,
      y0b + t*512, 28ll*512,
      US(OFF_WCAT0) + 1536ll*544, 544, 17, 1, s == 0,
      FP(OFF_BRZ0) + 1024, FP(OFF_BNIH0) + 512, FP(OFF_BNHH0) + 512);
  }

  // ---- phase B: layer-0 forward + layer-1 forward interleaved ----
  for (int s = 0; s < 28; ++s){
    gru_step_kernel<<<512, 512, 0, stream>>>(
      x + s*28, 784, nullptr, 0, 32, nullptr, 0, 0,
      h0bf + (s & 1)*PP, FP(OFF_H0F32), h0bf + ((s & 1) ^ 1)*PP,
      nullptr, 0,
      US(OFF_WCAT0), 544, 17, 1, s == 0,
      FP(OFF_BRZ0), FP(OFF_BNIH0), FP(OFF_BNHH0));

    gru_step_kernel<<<512, 512, 0, stream>>>(
      nullptr, 0,
      h0bf + ((s & 1) ^ 1)*PP, 512, 512,      // y0f slice = h0f output of this step
      y0b + s*512, 28ll*512, 512,             // y0b slice
      h1bf + (s & 1)*PP, FP(OFF_H1F32), h1bf + ((s & 1) ^ 1)*PP,
      nullptr, 0,
      US(OFF_WCAT1), 1536, 48, 32, s == 0,
      FP(OFF_BRZ1), FP(OFF_BNIH1), FP(OFF_BNHH1));
  }

  // ---- layer-1 backward: single step from h=0 on [y0f(27)|y0b(27)] ----
  gru_step_kernel<<<512, 512, 0, stream>>>(
    nullptr, 0,
    h0bf + 0*PP, 512, 512,                    // y0f t=27 (l0f(27) wrote pp buffer 0)
    y0b + 27*512, 28ll*512, 512,
    h1bf, FP(OFF_H1F32), US(OFF_H1BBF),
    nullptr, 0,
    US(OFF_W1R), 1024, 32, 32, 1,
    FP(OFF_BRZ1R), FP(OFF_BNIH1R), FP(OFF_BNHH1R));

  // ---- head (final h1f is pp buffer 0 after 28 steps) ----
  head_kernel<<<128, 512, 0, stream>>>(
    h1bf, US(OFF_H1BBF), US(OFF_FC1W), US(OFF_FC2W),
    FP(OFF_SC2), FP(OFF_SH2), FP(OFF_FC2B), (float*)d_out);
}

// Round 5
// 8884.077 us; speedup vs baseline: 2.9176x; 2.9176x over previous
//
#include <hip/hip_runtime.h>

#define DEV __device__ __forceinline__
typedef unsigned short us;
typedef __bf16 bf8 __attribute__((ext_vector_type(8)));
typedef float  f4  __attribute__((ext_vector_type(4)));

DEV us f2bf(float f){
  unsigned int u = __builtin_bit_cast(unsigned int, f);
  u = u + 0x7fffu + ((u >> 16) & 1u);
  return (us)(u >> 16);
}
DEV float sigm(float x){ return 1.f/(1.f + __expf(-x)); }
DEV bf8 ldb(const us* p){ return *reinterpret_cast<const bf8*>(p); }
DEV f4 mfma(bf8 a, bf8 b, f4 c){ return __builtin_amdgcn_mfma_f32_16x16x32_bf16(a, b, c, 0, 0, 0); }

// ---------------- workspace layout (bytes) — total ~171 MB
constexpr size_t OFF_WCAT0  = 0;                            // [2][1536][576] bf16 (K padded even)
constexpr size_t OFF_WCAT1  = OFF_WCAT0 + 2ull*1536*576*2;  // [1536][1536] bf16
constexpr size_t OFF_W1R    = OFF_WCAT1 + 1536ull*1536*2;   // [1536][1024] bf16
constexpr size_t OFF_FC1W   = OFF_W1R   + 1536ull*1024*2;   // [256][1024] bf16
constexpr size_t OFF_FC2W   = OFF_FC1W  + 256ull*1024*2;    // [16][256] bf16
constexpr size_t OFF_BRZ0   = OFF_FC2W  + 16ull*256*2;      // [2][1024] f32
constexpr size_t OFF_BNIH0  = OFF_BRZ0  + 2*1024*4;         // [2][512]
constexpr size_t OFF_BNHH0  = OFF_BNIH0 + 2*512*4;          // [2][512]
constexpr size_t OFF_BRZ1   = OFF_BNHH0 + 2*512*4;          // [1024]
constexpr size_t OFF_BNIH1  = OFF_BRZ1  + 1024*4;           // [512]
constexpr size_t OFF_BNHH1  = OFF_BNIH1 + 512*4;            // [512]
constexpr size_t OFF_BRZ1R  = OFF_BNHH1 + 512*4;            // [1024]
constexpr size_t OFF_BNIH1R = OFF_BRZ1R + 1024*4;           // [512]
constexpr size_t OFF_BNHH1R = OFF_BNIH1R+ 512*4;            // [512]
constexpr size_t OFF_SC2    = OFF_BNHH1R+ 512*4;            // [256]
constexpr size_t OFF_SH2    = OFF_SC2   + 256*4;            // [256]
constexpr size_t OFF_FC2B   = OFF_SH2   + 256*4;            // [16]
constexpr size_t OFF_Y0B    = OFF_FC2B  + 64;               // [4096][28][512] bf16
constexpr size_t OFF_H0BF   = OFF_Y0B   + 4096ull*28*512*2; // [2pp][4096][512] bf16
constexpr size_t OFF_H0F32  = OFF_H0BF  + 2ull*4096*512*2;  // [4096][512] f32
constexpr size_t OFF_H1BF   = OFF_H0F32 + 4096ull*512*4;    // [2pp][4096][512] bf16
constexpr size_t OFF_H1F32  = OFF_H1BF  + 2ull*4096*512*2;  // [4096][512] f32
constexpr size_t OFF_H1BBF  = OFF_H1F32 + 4096ull*512*4;    // [4096][512] bf16

constexpr long PP = 4096ll*512;

// ---------------- K0: weight/bias prep ----------------
__global__ void prep_kernel(
  const float* __restrict__ Wih0, const float* __restrict__ Whh0,
  const float* __restrict__ bih0, const float* __restrict__ bhh0,
  const float* __restrict__ Wih0r,const float* __restrict__ Whh0r,
  const float* __restrict__ bih0r,const float* __restrict__ bhh0r,
  const float* __restrict__ Wih1, const float* __restrict__ Whh1,
  const float* __restrict__ bih1, const float* __restrict__ bhh1,
  const float* __restrict__ Wih1r,const float* __restrict__ bih1r,
  const float* __restrict__ bhh1r,
  const float* __restrict__ fc1w, const float* __restrict__ fc1b,
  const float* __restrict__ gma,  const float* __restrict__ bta,
  const float* __restrict__ mean, const float* __restrict__ var,
  const float* __restrict__ fc2w, const float* __restrict__ fc2b,
  us* __restrict__ wcat0, us* __restrict__ wcat1, us* __restrict__ w1r,
  us* __restrict__ fc1wb, us* __restrict__ fc2wp,
  float* __restrict__ brz0, float* __restrict__ bnih0, float* __restrict__ bnhh0,
  float* __restrict__ brz1, float* __restrict__ bnih1, float* __restrict__ bnhh1,
  float* __restrict__ brz1r,float* __restrict__ bnih1r,float* __restrict__ bnhh1r,
  float* __restrict__ sc2,  float* __restrict__ sh2,   float* __restrict__ fc2bp)
{
  const int tid = blockIdx.x * blockDim.x + threadIdx.x;
  const int np  = gridDim.x * blockDim.x;
  // layer-0 fused: [dir][1536][576]; cols 0..27 W_ih, 28..31 pad, 32..543 W_hh, 544..575 pad
  for (int i = tid; i < 2*1536*576; i += np){
    int d = i / (1536*576); int rem = i - d*(1536*576);
    int n = rem / 576, k = rem - n*576;
    const float* ih = d ? Wih0r : Wih0;
    const float* hh = d ? Whh0r : Whh0;
    float v = (k < 32) ? (k < 28 ? ih[n*28 + k] : 0.f)
                       : (k < 544 ? hh[n*512 + (k-32)] : 0.f);
    wcat0[i] = f2bf(v);
  }
  for (int i = tid; i < 1536*1536; i += np){
    int n = i / 1536, k = i - n*1536;
    float v = (k < 1024) ? Wih1[n*1024 + k] : Whh1[n*512 + (k-1024)];
    wcat1[i] = f2bf(v);
  }
  for (int i = tid; i < 1536*1024; i += np) w1r[i]   = f2bf(Wih1r[i]);
  for (int i = tid; i < 256*1024;  i += np) fc1wb[i] = f2bf(fc1w[i]);
  for (int i = tid; i < 16*256;    i += np){
    int n = i / 256; fc2wp[i] = (n < 10) ? f2bf(fc2w[i]) : (us)0;
  }
  for (int i = tid; i < 1024; i += np){
    brz0[i]        = bih0[i]  + bhh0[i];
    brz0[1024 + i] = bih0r[i] + bhh0r[i];
    brz1[i]        = bih1[i]  + bhh1[i];
    brz1r[i]       = bih1r[i] + bhh1r[i];
  }
  for (int i = tid; i < 512; i += np){
    bnih0[i]       = bih0[1024 + i];   bnhh0[i]       = bhh0[1024 + i];
    bnih0[512 + i] = bih0r[1024 + i];  bnhh0[512 + i] = bhh0r[1024 + i];
    bnih1[i]       = bih1[1024 + i];   bnhh1[i]       = bhh1[1024 + i];
    bnih1r[i]      = bih1r[1024 + i];  bnhh1r[i]      = bhh1r[1024 + i];
  }
  for (int i = tid; i < 256; i += np){
    float s = gma[i] * rsqrtf(var[i] + 1e-5f);
    sc2[i] = s;
    sh2[i] = (fc1b[i] - mean[i]) * s + bta[i];
  }
  for (int i = tid; i < 16; i += np) fc2bp[i] = (i < 10) ? fc2b[i] : 0.f;
}

// ---------------- generic GRU step ----------------
// One recurrent step as a 2D-tiled GEMM + gate epilogue.
// grid 512: hcb = bid&15 (32 h-cols; XCD-swizzled so each XCD holds only 2
// hc-tiles of B in its L2), nm = bid>>4 (M tile of 128). 8 waves: wm=w>>1, wn=w&1.
// A = [seg0 (K0, fp32-x if xf32) | seg1 (K1) | h (512) | zero-pad]; K = nk*32 (nk EVEN).
// n-gate: XN = chunks < kxn (swapped into accXN at boundary), HN after.
// Pipeline: 4 LDS bufs (chunk c -> buf c&3), pair-processed; A loads 2 barrier
// intervals ahead (uA<-vA rotation), B frags 2 chunks ahead. All pipeline regs
// are named scalars — NO dynamically-indexed register arrays (round-4 bug:
// vA[kt&1] went to scratch -> 61 MB spill traffic, 8x regression).
__global__ __launch_bounds__(512, 4) void gru_step_kernel(
  const float* __restrict__ xf32, long xstride,
  const us* __restrict__ src0, long s0stride, int K0,
  const us* __restrict__ src1, long s1stride, int K1,
  const us* __restrict__ hIn, float* __restrict__ hF, us* __restrict__ hOut,
  us* __restrict__ y, long ystride,
  const us* __restrict__ W, int Kw, int nk, int kxn, int first,
  const float* __restrict__ brz, const float* __restrict__ bni,
  const float* __restrict__ bnh)
{
  __shared__ us As[4*5120];   // 4 bufs of [128 rows][32 cols pad->40]

  const int tid = threadIdx.x, bid = blockIdx.x;
  const int hcb = bid & 15, nm = bid >> 4;
  const size_t Mbase = (size_t)nm * 128;
  const int hcBase = hcb * 32;
  const int K01 = K0 + K1;

  const int w = tid >> 6, lane = tid & 63, ln = lane & 15, lq = lane >> 4;
  const int wm = w >> 1, wn = w & 1;
  const int srow = tid >> 2, sgrp = tid & 3;
  const size_t mrow = Mbase + srow;

  const us* pB0 = W + (size_t)(       hcBase + wn*16 + ln) * Kw + lq*8;
  const us* pB1 = W + (size_t)( 512 + hcBase + wn*16 + ln) * Kw + lq*8;
  const us* pB2 = W + (size_t)(1024 + hcBase + wn*16 + ln) * Kw + lq*8;

  auto loadA = [&](int c) -> uint4 {
    const int col = c*32 + sgrp*8;
    if (col < K0){
      if (xf32){
        const float* xr = xf32 + mrow*xstride;
        us t8[8];
        #pragma unroll
        for (int j = 0; j < 8; ++j){
          int cc = col + j;
          t8[j] = (cc < 28) ? f2bf(xr[cc]) : (us)0;
        }
        return *reinterpret_cast<uint4*>(t8);
      }
      return *reinterpret_cast<const uint4*>(src0 + mrow*s0stride + col);
    }
    if (col < K01)
      return *reinterpret_cast<const uint4*>(src1 + mrow*s1stride + (col - K0));
    if (col < K01 + 512 && !first)
      return *reinterpret_cast<const uint4*>(hIn + mrow*512 + (col - K01));
    return uint4{0,0,0,0};
  };
  auto stA = [&](int c, uint4 v){
    *reinterpret_cast<uint4*>(&As[(c & 3)*5120 + srow*40 + sgrp*8]) = v;
  };

  // ---- prologue (nk even, >= 6 for all call sites: 18/32/48)
  stA(0, loadA(0));
  stA(1, loadA(1));
  uint4 uA0 = loadA(2), uA1 = loadA(3);
  uint4 vA0 = loadA(4), vA1 = loadA(5);
  bf8 bR0 = ldb(pB0),      bZ0 = ldb(pB1),      bN0 = ldb(pB2);
  bf8 bR1 = ldb(pB0 + 32), bZ1 = ldb(pB1 + 32), bN1 = ldb(pB2 + 32);
  bf8 nR0 = ldb(pB0 + 64), nZ0 = ldb(pB1 + 64), nN0 = ldb(pB2 + 64);
  bf8 nR1 = ldb(pB0 + 96), nZ1 = ldb(pB1 + 96), nN1 = ldb(pB2 + 96);
  __syncthreads();

  f4 accR[2] = {}, accZ[2] = {}, accN[2] = {}, accXN[2] = {};

  for (int kt = 0; kt < nk; kt += 2){
    const int b0 = (kt & 3)*5120, b1 = ((kt + 1) & 3)*5120;
    // chunk kt
    bf8 a0 = ldb(&As[b0 + (wm*32 +  0 + ln)*40 + lq*8]);
    bf8 a1 = ldb(&As[b0 + (wm*32 + 16 + ln)*40 + lq*8]);
    accR[0] = mfma(a0, bR0, accR[0]); accR[1] = mfma(a1, bR0, accR[1]);
    accZ[0] = mfma(a0, bZ0, accZ[0]); accZ[1] = mfma(a1, bZ0, accZ[1]);
    accN[0] = mfma(a0, bN0, accN[0]); accN[1] = mfma(a1, bN0, accN[1]);
    if (kt == kxn - 1){
      accXN[0] = accN[0]; accXN[1] = accN[1];
      accN[0] = f4{0.f,0.f,0.f,0.f}; accN[1] = f4{0.f,0.f,0.f,0.f};
    }
    // chunk kt+1
    bf8 a2 = ldb(&As[b1 + (wm*32 +  0 + ln)*40 + lq*8]);
    bf8 a3 = ldb(&As[b1 + (wm*32 + 16 + ln)*40 + lq*8]);
    accR[0] = mfma(a2, bR1, accR[0]); accR[1] = mfma(a3, bR1, accR[1]);
    accZ[0] = mfma(a2, bZ1, accZ[0]); accZ[1] = mfma(a3, bZ1, accZ[1]);
    accN[0] = mfma(a2, bN1, accN[0]); accN[1] = mfma(a3, bN1, accN[1]);
    if (kt + 1 == kxn - 1){
      accXN[0] = accN[0]; accXN[1] = accN[1];
      accN[0] = f4{0.f,0.f,0.f,0.f}; accN[1] = f4{0.f,0.f,0.f,0.f};
    }
    // rotate B (named regs, compile-time)
    bR0 = nR0; bZ0 = nZ0; bN0 = nN0;
    bR1 = nR1; bZ1 = nZ1; bN1 = nN1;
    if (kt + 2 < nk){
      stA(kt + 2, uA0);               // loads issued 2 barrier intervals ago
      stA(kt + 3, uA1);
      uA0 = vA0; uA1 = vA1;
      vA0 = (kt + 6 < nk) ? loadA(kt + 6) : uint4{0,0,0,0};
      vA1 = (kt + 7 < nk) ? loadA(kt + 7) : uint4{0,0,0,0};
      if (kt + 4 < nk){
        const int kc = (kt + 4) * 32;
        nR0 = ldb(pB0 + kc);      nZ0 = ldb(pB1 + kc);      nN0 = ldb(pB2 + kc);
        nR1 = ldb(pB0 + kc + 32); nZ1 = ldb(pB1 + kc + 32); nN1 = ldb(pB2 + kc + 32);
      }
      __syncthreads();
    }
  }

  // ---- gate epilogue ----
  const int c = hcBase + wn*16 + ln;
  const float br = brz[c], bz = brz[512 + c], bi = bni[c], bh = bnh[c];
  #pragma unroll
  for (int mt = 0; mt < 2; ++mt){
    #pragma unroll
    for (int e = 0; e < 4; ++e){
      const size_t m = Mbase + wm*32 + mt*16 + lq*4 + e;
      float r = sigm(accR[mt][e] + br);
      float z = sigm(accZ[mt][e] + bz);
      float n = tanhf(accXN[mt][e] + bi + r*(accN[mt][e] + bh));
      float hprev = first ? 0.f : hF[m*512 + c];
      float h = (1.f - z)*n + z*hprev;
      hF[m*512 + c] = h;
      us hb = f2bf(h);
      hOut[m*512 + c] = hb;
      if (y) y[m*ystride + c] = hb;
    }
  }
}

// ---------------- head: [h1f|h1b] -> fc1 -> bn/relu -> fc2 -> log_softmax ----
__global__ __launch_bounds__(512) void head_kernel(
  const us* __restrict__ h1f, const us* __restrict__ h1b,
  const us* __restrict__ fc1w, const us* __restrict__ fc2wp,
  const float* __restrict__ sc2, const float* __restrict__ sh2,
  const float* __restrict__ fc2b, float* __restrict__ out)
{
  constexpr int APS = 1048;
  __shared__ us As[32 * APS];
  __shared__ us actS[32 * 264];
  __shared__ float lg[32 * 16];
  const int tid = threadIdx.x;
  const size_t row0 = (size_t)blockIdx.x * 32;
  const int w = tid >> 6, lane = tid & 63, ln = lane & 15, lq = lane >> 4;

  for (int i = tid; i < 32*128; i += 512){
    int r = i >> 7, g = i & 127, col = g*8;
    uint4 v = (col < 512)
      ? *reinterpret_cast<const uint4*>(h1f + (row0 + r)*512 + col)
      : *reinterpret_cast<const uint4*>(h1b + (row0 + r)*512 + (col - 512));
    *reinterpret_cast<uint4*>(&As[r*APS + col]) = v;
  }
  __syncthreads();

  {
    f4 acc[2][2] = {};
    for (int kt = 0; kt < 32; ++kt){
      const int kc = kt*32 + lq*8;
      bf8 a0 = ldb(&As[ln*APS + kc]);
      bf8 a1 = ldb(&As[(16 + ln)*APS + kc]);
      #pragma unroll
      for (int nt = 0; nt < 2; ++nt){
        const int col = w*32 + nt*16 + ln;
        bf8 b = ldb(&fc1w[(size_t)col*1024 + kc]);
        acc[0][nt] = mfma(a0, b, acc[0][nt]);
        acc[1][nt] = mfma(a1, b, acc[1][nt]);
      }
    }
    #pragma unroll
    for (int nt = 0; nt < 2; ++nt){
      const int col = w*32 + nt*16 + ln;
      const float sc = sc2[col], sh = sh2[col];
      #pragma unroll
      for (int mt = 0; mt < 2; ++mt)
        #pragma unroll
        for (int e = 0; e < 4; ++e){
          float v = fmaxf(acc[mt][nt][e]*sc + sh, 0.f);
          actS[(mt*16 + lq*4 + e)*264 + col] = f2bf(v);
        }
    }
    __syncthreads();
  }

  if (w == 0){
    f4 acc[2] = {};
    for (int kt = 0; kt < 8; ++kt){
      const int kc = kt*32 + lq*8;
      bf8 a0 = ldb(&actS[ln*264 + kc]);
      bf8 a1 = ldb(&actS[(16 + ln)*264 + kc]);
      bf8 b  = ldb(&fc2wp[ln*256 + kc]);
      acc[0] = mfma(a0, b, acc[0]);
      acc[1] = mfma(a1, b, acc[1]);
    }
    const float bb = fc2b[ln];
    #pragma unroll
    for (int mt = 0; mt < 2; ++mt)
      #pragma unroll
      for (int e = 0; e < 4; ++e)
        lg[(mt*16 + lq*4 + e)*16 + ln] = acc[mt][e] + bb;
  }
  __syncthreads();
  if (tid < 32){
    const int r = tid;
    float mx = -1e30f;
    for (int cc = 0; cc < 10; ++cc) mx = fmaxf(mx, lg[r*16 + cc]);
    float sum = 0.f;
    for (int cc = 0; cc < 10; ++cc) sum += __expf(lg[r*16 + cc] - mx);
    const float lse = mx + logf(sum);
    for (int cc = 0; cc < 10; ++cc)
      out[(row0 + r)*10 + cc] = lg[r*16 + cc] - lse;
  }
}

// ---------------- launch ----------------
extern "C" void kernel_launch(void* const* d_in, const int* in_sizes, int n_in,
                              void* d_out, int out_size, void* d_ws, size_t ws_size,
                              hipStream_t stream)
{
  (void)in_sizes; (void)n_in; (void)out_size; (void)ws_size;
  char* ws = (char*)d_ws;
  auto US = [&](size_t off){ return (us*)(ws + off); };
  auto FP = [&](size_t off){ return (float*)(ws + off); };

  const float* x      = (const float*)d_in[0];
  const float* Wih0   = (const float*)d_in[1];
  const float* Whh0   = (const float*)d_in[2];
  const float* bih0   = (const float*)d_in[3];
  const float* bhh0   = (const float*)d_in[4];
  const float* Wih0r  = (const float*)d_in[5];
  const float* Whh0r  = (const float*)d_in[6];
  const float* bih0r  = (const float*)d_in[7];
  const float* bhh0r  = (const float*)d_in[8];
  const float* Wih1   = (const float*)d_in[9];
  const float* Whh1   = (const float*)d_in[10];
  const float* bih1   = (const float*)d_in[11];
  const float* bhh1   = (const float*)d_in[12];
  const float* Wih1r  = (const float*)d_in[13];
  // d_in[14] (W_hh_l1r) unused: backward layer-1 runs exactly one step from h=0.
  const float* bih1r  = (const float*)d_in[15];
  const float* bhh1r  = (const float*)d_in[16];
  const float* fc1w   = (const float*)d_in[17];
  const float* fc1b   = (const float*)d_in[18];
  const float* gma    = (const float*)d_in[19];
  const float* bta    = (const float*)d_in[20];
  const float* mean   = (const float*)d_in[21];
  const float* var    = (const float*)d_in[22];
  const float* fc2w   = (const float*)d_in[23];
  const float* fc2b   = (const float*)d_in[24];

  prep_kernel<<<512, 256, 0, stream>>>(
    Wih0, Whh0, bih0, bhh0, Wih0r, Whh0r, bih0r, bhh0r,
    Wih1, Whh1, bih1, bhh1, Wih1r, bih1r, bhh1r,
    fc1w, fc1b, gma, bta, mean, var, fc2w, fc2b,
    US(OFF_WCAT0), US(OFF_WCAT1), US(OFF_W1R), US(OFF_FC1W), US(OFF_FC2W),
    FP(OFF_BRZ0), FP(OFF_BNIH0), FP(OFF_BNHH0),
    FP(OFF_BRZ1), FP(OFF_BNIH1), FP(OFF_BNHH1),
    FP(OFF_BRZ1R), FP(OFF_BNIH1R), FP(OFF_BNHH1R),
    FP(OFF_SC2), FP(OFF_SH2), FP(OFF_FC2B));

  us* y0b  = US(OFF_Y0B);
  us* h0bf = US(OFF_H0BF);
  us* h1bf = US(OFF_H1BF);

  // ---- phase A: layer-0 backward (materialize y0b) ----
  for (int s = 0; s < 28; ++s){
    const int t = 27 - s;
    gru_step_kernel<<<512, 512, 0, stream>>>(
      x + t*28, 784, nullptr, 0, 32, nullptr, 0, 0,
      h0bf + (s & 1)*PP, FP(OFF_H0F32), h0bf + ((s & 1) ^ 1)*PP,
      y0b + t*512, 28ll*512,
      US(OFF_WCAT0) + 1536ll*576, 576, 18, 1, s == 0,
      FP(OFF_BRZ0) + 1024, FP(OFF_BNIH0) + 512, FP(OFF_BNHH0) + 512);
  }

  // ---- phase B: layer-0 forward + layer-1 forward interleaved ----
  for (int s = 0; s < 28; ++s){
    gru_step_kernel<<<512, 512, 0, stream>>>(
      x + s*28, 784, nullptr, 0, 32, nullptr, 0, 0,
      h0bf + (s & 1)*PP, FP(OFF_H0F32), h0bf + ((s & 1) ^ 1)*PP,
      nullptr, 0,
      US(OFF_WCAT0), 576, 18, 1, s == 0,
      FP(OFF_BRZ0), FP(OFF_BNIH0), FP(OFF_BNHH0));

    gru_step_kernel<<<512, 512, 0, stream>>>(
      nullptr, 0,
      h0bf + ((s & 1) ^ 1)*PP, 512, 512,      // y0f slice = h0f output of this step
      y0b + s*512, 28ll*512, 512,             // y0b slice
      h1bf + (s & 1)*PP, FP(OFF_H1F32), h1bf + ((s & 1) ^ 1)*PP,
      nullptr, 0,
      US(OFF_WCAT1), 1536, 48, 32, s == 0,
      FP(OFF_BRZ1), FP(OFF_BNIH1), FP(OFF_BNHH1));
  }

  // ---- layer-1 backward: single step from h=0 on [y0f(27)|y0b(27)] ----
  gru_step_kernel<<<512, 512, 0, stream>>>(
    nullptr, 0,
    h0bf + 0*PP, 512, 512,                    // y0f t=27 (l0f(27) wrote pp buffer 0)
    y0b + 27*512, 28ll*512, 512,
    h1bf, FP(OFF_H1F32), US(OFF_H1BBF),
    nullptr, 0,
    US(OFF_W1R), 1024, 32, 32, 1,
    FP(OFF_BRZ1R), FP(OFF_BNIH1R), FP(OFF_BNHH1R));

  // ---- head (final h1f is pp buffer 0 after 28 steps) ----
  head_kernel<<<128, 512, 0, stream>>>(
    h1bf, US(OFF_H1BBF), US(OFF_FC1W), US(OFF_FC2W),
    FP(OFF_SC2), FP(OFF_SH2), FP(OFF_FC2B), (float*)d_out);
}

// Round 6
// 4499.591 us; speedup vs baseline: 5.7605x; 1.9744x over previous
//
#include <hip/hip_runtime.h>

#define DEV __device__ __forceinline__
typedef unsigned short us;
typedef __bf16 bf8 __attribute__((ext_vector_type(8)));
typedef float  f4  __attribute__((ext_vector_type(4)));

DEV us f2bf(float f){
  unsigned int u = __builtin_bit_cast(unsigned int, f);
  u = u + 0x7fffu + ((u >> 16) & 1u);
  return (us)(u >> 16);
}
DEV float sigm(float x){ return 1.f/(1.f + __expf(-x)); }
DEV bf8 ldb(const us* p){ return *reinterpret_cast<const bf8*>(p); }
DEV f4 mfma(bf8 a, bf8 b, f4 c){ return __builtin_amdgcn_mfma_f32_16x16x32_bf16(a, b, c, 0, 0, 0); }

// ---------------- workspace layout (bytes) — total ~171 MB
constexpr size_t OFF_WCAT0  = 0;                            // [2][1536][576] bf16
constexpr size_t OFF_WCAT1  = OFF_WCAT0 + 2ull*1536*576*2;  // [1536][1536] bf16
constexpr size_t OFF_W1R    = OFF_WCAT1 + 1536ull*1536*2;   // [1536][1024] bf16
constexpr size_t OFF_FC1W   = OFF_W1R   + 1536ull*1024*2;   // [256][1024] bf16
constexpr size_t OFF_FC2W   = OFF_FC1W  + 256ull*1024*2;    // [16][256] bf16
constexpr size_t OFF_BRZ0   = OFF_FC2W  + 16ull*256*2;      // [2][1024] f32
constexpr size_t OFF_BNIH0  = OFF_BRZ0  + 2*1024*4;         // [2][512]
constexpr size_t OFF_BNHH0  = OFF_BNIH0 + 2*512*4;          // [2][512]
constexpr size_t OFF_BRZ1   = OFF_BNHH0 + 2*512*4;          // [1024]
constexpr size_t OFF_BNIH1  = OFF_BRZ1  + 1024*4;           // [512]
constexpr size_t OFF_BNHH1  = OFF_BNIH1 + 512*4;            // [512]
constexpr size_t OFF_BRZ1R  = OFF_BNHH1 + 512*4;            // [1024]
constexpr size_t OFF_BNIH1R = OFF_BRZ1R + 1024*4;           // [512]
constexpr size_t OFF_BNHH1R = OFF_BNIH1R+ 512*4;            // [512]
constexpr size_t OFF_SC2    = OFF_BNHH1R+ 512*4;            // [256]
constexpr size_t OFF_SH2    = OFF_SC2   + 256*4;            // [256]
constexpr size_t OFF_FC2B   = OFF_SH2   + 256*4;            // [16]
constexpr size_t OFF_Y0B    = OFF_FC2B  + 64;               // [4096][28][512] bf16
constexpr size_t OFF_H0BF   = OFF_Y0B   + 4096ull*28*512*2; // [2pp][4096][512] bf16
constexpr size_t OFF_H0F32  = OFF_H0BF  + 2ull*4096*512*2;  // [4096][512] f32
constexpr size_t OFF_H1BF   = OFF_H0F32 + 4096ull*512*4;    // [2pp][4096][512] bf16
constexpr size_t OFF_H1F32  = OFF_H1BF  + 2ull*4096*512*2;  // [4096][512] f32
constexpr size_t OFF_H1BBF  = OFF_H1F32 + 4096ull*512*4;    // [4096][512] bf16

constexpr long PP = 4096ll*512;

// ---------------- K0: weight/bias prep ----------------
__global__ void prep_kernel(
  const float* __restrict__ Wih0, const float* __restrict__ Whh0,
  const float* __restrict__ bih0, const float* __restrict__ bhh0,
  const float* __restrict__ Wih0r,const float* __restrict__ Whh0r,
  const float* __restrict__ bih0r,const float* __restrict__ bhh0r,
  const float* __restrict__ Wih1, const float* __restrict__ Whh1,
  const float* __restrict__ bih1, const float* __restrict__ bhh1,
  const float* __restrict__ Wih1r,const float* __restrict__ bih1r,
  const float* __restrict__ bhh1r,
  const float* __restrict__ fc1w, const float* __restrict__ fc1b,
  const float* __restrict__ gma,  const float* __restrict__ bta,
  const float* __restrict__ mean, const float* __restrict__ var,
  const float* __restrict__ fc2w, const float* __restrict__ fc2b,
  us* __restrict__ wcat0, us* __restrict__ wcat1, us* __restrict__ w1r,
  us* __restrict__ fc1wb, us* __restrict__ fc2wp,
  float* __restrict__ brz0, float* __restrict__ bnih0, float* __restrict__ bnhh0,
  float* __restrict__ brz1, float* __restrict__ bnih1, float* __restrict__ bnhh1,
  float* __restrict__ brz1r,float* __restrict__ bnih1r,float* __restrict__ bnhh1r,
  float* __restrict__ sc2,  float* __restrict__ sh2,   float* __restrict__ fc2bp)
{
  const int tid = blockIdx.x * blockDim.x + threadIdx.x;
  const int np  = gridDim.x * blockDim.x;
  // layer-0 fused: [dir][1536][576]; cols 0..27 W_ih, 28..31 pad, 32..543 W_hh, 544..575 pad
  for (int i = tid; i < 2*1536*576; i += np){
    int d = i / (1536*576); int rem = i - d*(1536*576);
    int n = rem / 576, k = rem - n*576;
    const float* ih = d ? Wih0r : Wih0;
    const float* hh = d ? Whh0r : Whh0;
    float v = (k < 32) ? (k < 28 ? ih[n*28 + k] : 0.f)
                       : (k < 544 ? hh[n*512 + (k-32)] : 0.f);
    wcat0[i] = f2bf(v);
  }
  for (int i = tid; i < 1536*1536; i += np){
    int n = i / 1536, k = i - n*1536;
    float v = (k < 1024) ? Wih1[n*1024 + k] : Whh1[n*512 + (k-1024)];
    wcat1[i] = f2bf(v);
  }
  for (int i = tid; i < 1536*1024; i += np) w1r[i]   = f2bf(Wih1r[i]);
  for (int i = tid; i < 256*1024;  i += np) fc1wb[i] = f2bf(fc1w[i]);
  for (int i = tid; i < 16*256;    i += np){
    int n = i / 256; fc2wp[i] = (n < 10) ? f2bf(fc2w[i]) : (us)0;
  }
  for (int i = tid; i < 1024; i += np){
    brz0[i]        = bih0[i]  + bhh0[i];
    brz0[1024 + i] = bih0r[i] + bhh0r[i];
    brz1[i]        = bih1[i]  + bhh1[i];
    brz1r[i]       = bih1r[i] + bhh1r[i];
  }
  for (int i = tid; i < 512; i += np){
    bnih0[i]       = bih0[1024 + i];   bnhh0[i]       = bhh0[1024 + i];
    bnih0[512 + i] = bih0r[1024 + i];  bnhh0[512 + i] = bhh0r[1024 + i];
    bnih1[i]       = bih1[1024 + i];   bnhh1[i]       = bhh1[1024 + i];
    bnih1r[i]      = bih1r[1024 + i];  bnhh1r[i]      = bhh1r[1024 + i];
  }
  for (int i = tid; i < 256; i += np){
    float s = gma[i] * rsqrtf(var[i] + 1e-5f);
    sc2[i] = s;
    sh2[i] = (fc1b[i] - mean[i]) * s + bta[i];
  }
  for (int i = tid; i < 16; i += np) fc2bp[i] = (i < 10) ? fc2b[i] : 0.f;
}

// ---------------- generic GRU step ----------------
// One recurrent step as a 2D-tiled GEMM + gate epilogue.
// grid 512: hcb = bid&7 (64 h-cols), nm = bid>>3 (M tile of 64) -> 2 blocks/CU.
// 8 waves: wm = w>>2 (32 M rows), wn = w&3 (16 hc).
// A = [seg0 (K0, fp32-x if xf32) | seg1 (K1) | h (512) | zero-pad]; K = nk*32.
// n-gate: XN = chunks < kxn (swapped into accXN regs at boundary), HN after.
// Round-3-proven no-spill loop: LDS double-buffer, distance-1 prefetch,
// ONE sync per iteration. NO __launch_bounds__ min-waves (round-4/5 bug:
// forced 64-VGPR cap -> per-iteration scratch spill, 61-310 MB/dispatch).
__global__ __launch_bounds__(512) void gru_step_kernel(
  const float* __restrict__ xf32, long xstride,
  const us* __restrict__ src0, long s0stride, int K0,
  const us* __restrict__ src1, long s1stride, int K1,
  const us* __restrict__ hIn, float* __restrict__ hF, us* __restrict__ hOut,
  us* __restrict__ y, long ystride,
  const us* __restrict__ W, int Kw, int nk, int kxn, int first,
  const float* __restrict__ brz, const float* __restrict__ bni,
  const float* __restrict__ bnh)
{
  __shared__ us As[2*2560];   // 2 bufs of [64 rows][32 cols pad->40]

  const int tid = threadIdx.x, bid = blockIdx.x;
  const int hcb = bid & 7, nm = bid >> 3;
  const size_t Mbase = (size_t)nm * 64;
  const int hcBase = hcb * 64;
  const int K01 = K0 + K1;

  const int w = tid >> 6, lane = tid & 63, ln = lane & 15, lq = lane >> 4;
  const int wm = w >> 2, wn = w & 3;
  const int srow = tid >> 2, sgrp = tid & 3;   // staging (tid < 256): 64 rows x 4 grps
  const size_t mrow = Mbase + srow;

  const us* pB0 = W + (size_t)(       hcBase + wn*16 + ln) * Kw + lq*8;
  const us* pB1 = W + (size_t)( 512 + hcBase + wn*16 + ln) * Kw + lq*8;
  const us* pB2 = W + (size_t)(1024 + hcBase + wn*16 + ln) * Kw + lq*8;

  auto loadA = [&](int c) -> uint4 {
    const int col = c*32 + sgrp*8;
    if (col < K0){
      if (xf32){
        const float* xr = xf32 + mrow*xstride;
        us t8[8];
        #pragma unroll
        for (int j = 0; j < 8; ++j){
          int cc = col + j;
          t8[j] = (cc < 28) ? f2bf(xr[cc]) : (us)0;
        }
        return *reinterpret_cast<uint4*>(t8);
      }
      return *reinterpret_cast<const uint4*>(src0 + mrow*s0stride + col);
    }
    if (col < K01)
      return *reinterpret_cast<const uint4*>(src1 + mrow*s1stride + (col - K0));
    if (col < K01 + 512 && !first)
      return *reinterpret_cast<const uint4*>(hIn + mrow*512 + (col - K01));
    return uint4{0,0,0,0};
  };
  auto stA = [&](int buf, uint4 v){
    *reinterpret_cast<uint4*>(&As[buf + srow*40 + sgrp*8]) = v;
  };

  // ---- prologue
  if (tid < 256) stA(0, loadA(0));
  bf8 bR = ldb(pB0), bZ = ldb(pB1), bN = ldb(pB2);
  __syncthreads();

  f4 accR[2] = {}, accZ[2] = {}, accN[2] = {}, accXN[2] = {};

  for (int kt = 0; kt < nk; ++kt){
    const int buf = (kt & 1) * 2560;
    const bool more = (kt + 1) < nk;
    bf8 bR2, bZ2, bN2; uint4 nv;
    if (more){
      const int kc = (kt + 1) * 32;
      bR2 = ldb(pB0 + kc); bZ2 = ldb(pB1 + kc); bN2 = ldb(pB2 + kc);
      if (tid < 256) nv = loadA(kt + 1);
    }
    bf8 a0 = ldb(&As[buf + (wm*32 +  0 + ln)*40 + lq*8]);
    bf8 a1 = ldb(&As[buf + (wm*32 + 16 + ln)*40 + lq*8]);
    accR[0] = mfma(a0, bR, accR[0]); accR[1] = mfma(a1, bR, accR[1]);
    accZ[0] = mfma(a0, bZ, accZ[0]); accZ[1] = mfma(a1, bZ, accZ[1]);
    accN[0] = mfma(a0, bN, accN[0]); accN[1] = mfma(a1, bN, accN[1]);
    if (kt == kxn - 1){
      accXN[0] = accN[0]; accXN[1] = accN[1];
      accN[0] = f4{0.f,0.f,0.f,0.f}; accN[1] = f4{0.f,0.f,0.f,0.f};
    }
    if (more){
      if (tid < 256) stA(buf ^ 2560, nv);
      __syncthreads();
      bR = bR2; bZ = bZ2; bN = bN2;
    }
  }

  // ---- gate epilogue ----
  const int c = hcBase + wn*16 + ln;
  const float br = brz[c], bz = brz[512 + c], bi = bni[c], bh = bnh[c];
  #pragma unroll
  for (int mt = 0; mt < 2; ++mt){
    #pragma unroll
    for (int e = 0; e < 4; ++e){
      const size_t m = Mbase + wm*32 + mt*16 + lq*4 + e;
      float r = sigm(accR[mt][e] + br);
      float z = sigm(accZ[mt][e] + bz);
      float n = tanhf(accXN[mt][e] + bi + r*(accN[mt][e] + bh));
      float hprev = first ? 0.f : hF[m*512 + c];
      float h = (1.f - z)*n + z*hprev;
      hF[m*512 + c] = h;
      us hb = f2bf(h);
      hOut[m*512 + c] = hb;
      if (y) y[m*ystride + c] = hb;
    }
  }
}

// ---------------- head: [h1f|h1b] -> fc1 -> bn/relu -> fc2 -> log_softmax ----
__global__ __launch_bounds__(512) void head_kernel(
  const us* __restrict__ h1f, const us* __restrict__ h1b,
  const us* __restrict__ fc1w, const us* __restrict__ fc2wp,
  const float* __restrict__ sc2, const float* __restrict__ sh2,
  const float* __restrict__ fc2b, float* __restrict__ out)
{
  constexpr int APS = 1048;
  __shared__ us As[32 * APS];
  __shared__ us actS[32 * 264];
  __shared__ float lg[32 * 16];
  const int tid = threadIdx.x;
  const size_t row0 = (size_t)blockIdx.x * 32;
  const int w = tid >> 6, lane = tid & 63, ln = lane & 15, lq = lane >> 4;

  for (int i = tid; i < 32*128; i += 512){
    int r = i >> 7, g = i & 127, col = g*8;
    uint4 v = (col < 512)
      ? *reinterpret_cast<const uint4*>(h1f + (row0 + r)*512 + col)
      : *reinterpret_cast<const uint4*>(h1b + (row0 + r)*512 + (col - 512));
    *reinterpret_cast<uint4*>(&As[r*APS + col]) = v;
  }
  __syncthreads();

  {
    f4 acc[2][2] = {};
    for (int kt = 0; kt < 32; ++kt){
      const int kc = kt*32 + lq*8;
      bf8 a0 = ldb(&As[ln*APS + kc]);
      bf8 a1 = ldb(&As[(16 + ln)*APS + kc]);
      #pragma unroll
      for (int nt = 0; nt < 2; ++nt){
        const int col = w*32 + nt*16 + ln;
        bf8 b = ldb(&fc1w[(size_t)col*1024 + kc]);
        acc[0][nt] = mfma(a0, b, acc[0][nt]);
        acc[1][nt] = mfma(a1, b, acc[1][nt]);
      }
    }
    #pragma unroll
    for (int nt = 0; nt < 2; ++nt){
      const int col = w*32 + nt*16 + ln;
      const float sc = sc2[col], sh = sh2[col];
      #pragma unroll
      for (int mt = 0; mt < 2; ++mt)
        #pragma unroll
        for (int e = 0; e < 4; ++e){
          float v = fmaxf(acc[mt][nt][e]*sc + sh, 0.f);
          actS[(mt*16 + lq*4 + e)*264 + col] = f2bf(v);
        }
    }
    __syncthreads();
  }

  if (w == 0){
    f4 acc[2] = {};
    for (int kt = 0; kt < 8; ++kt){
      const int kc = kt*32 + lq*8;
      bf8 a0 = ldb(&actS[ln*264 + kc]);
      bf8 a1 = ldb(&actS[(16 + ln)*264 + kc]);
      bf8 b  = ldb(&fc2wp[ln*256 + kc]);
      acc[0] = mfma(a0, b, acc[0]);
      acc[1] = mfma(a1, b, acc[1]);
    }
    const float bb = fc2b[ln];
    #pragma unroll
    for (int mt = 0; mt < 2; ++mt)
      #pragma unroll
      for (int e = 0; e < 4; ++e)
        lg[(mt*16 + lq*4 + e)*16 + ln] = acc[mt][e] + bb;
  }
  __syncthreads();
  if (tid < 32){
    const int r = tid;
    float mx = -1e30f;
    for (int cc = 0; cc < 10; ++cc) mx = fmaxf(mx, lg[r*16 + cc]);
    float sum = 0.f;
    for (int cc = 0; cc < 10; ++cc) sum += __expf(lg[r*16 + cc] - mx);
    const float lse = mx + logf(sum);
    for (int cc = 0; cc < 10; ++cc)
      out[(row0 + r)*10 + cc] = lg[r*16 + cc] - lse;
  }
}

// ---------------- launch ----------------
extern "C" void kernel_launch(void* const* d_in, const int* in_sizes, int n_in,
                              void* d_out, int out_size, void* d_ws, size_t ws_size,
                              hipStream_t stream)
{
  (void)in_sizes; (void)n_in; (void)out_size; (void)ws_size;
  char* ws = (char*)d_ws;
  auto US = [&](size_t off){ return (us*)(ws + off); };
  auto FP = [&](size_t off){ return (float*)(ws + off); };

  const float* x      = (const float*)d_in[0];
  const float* Wih0   = (const float*)d_in[1];
  const float* Whh0   = (const float*)d_in[2];
  const float* bih0   = (const float*)d_in[3];
  const float* bhh0   = (const float*)d_in[4];
  const float* Wih0r  = (const float*)d_in[5];
  const float* Whh0r  = (const float*)d_in[6];
  const float* bih0r  = (const float*)d_in[7];
  const float* bhh0r  = (const float*)d_in[8];
  const float* Wih1   = (const float*)d_in[9];
  const float* Whh1   = (const float*)d_in[10];
  const float* bih1   = (const float*)d_in[11];
  const float* bhh1   = (const float*)d_in[12];
  const float* Wih1r  = (const float*)d_in[13];
  // d_in[14] (W_hh_l1r) unused: backward layer-1 runs exactly one step from h=0.
  const float* bih1r  = (const float*)d_in[15];
  const float* bhh1r  = (const float*)d_in[16];
  const float* fc1w   = (const float*)d_in[17];
  const float* fc1b   = (const float*)d_in[18];
  const float* gma    = (const float*)d_in[19];
  const float* bta    = (const float*)d_in[20];
  const float* mean   = (const float*)d_in[21];
  const float* var    = (const float*)d_in[22];
  const float* fc2w   = (const float*)d_in[23];
  const float* fc2b   = (const float*)d_in[24];

  prep_kernel<<<512, 256, 0, stream>>>(
    Wih0, Whh0, bih0, bhh0, Wih0r, Whh0r, bih0r, bhh0r,
    Wih1, Whh1, bih1, bhh1, Wih1r, bih1r, bhh1r,
    fc1w, fc1b, gma, bta, mean, var, fc2w, fc2b,
    US(OFF_WCAT0), US(OFF_WCAT1), US(OFF_W1R), US(OFF_FC1W), US(OFF_FC2W),
    FP(OFF_BRZ0), FP(OFF_BNIH0), FP(OFF_BNHH0),
    FP(OFF_BRZ1), FP(OFF_BNIH1), FP(OFF_BNHH1),
    FP(OFF_BRZ1R), FP(OFF_BNIH1R), FP(OFF_BNHH1R),
    FP(OFF_SC2), FP(OFF_SH2), FP(OFF_FC2B));

  us* y0b  = US(OFF_Y0B);
  us* h0bf = US(OFF_H0BF);
  us* h1bf = US(OFF_H1BF);

  // ---- phase A: layer-0 backward (materialize y0b) ----
  for (int s = 0; s < 28; ++s){
    const int t = 27 - s;
    gru_step_kernel<<<512, 512, 0, stream>>>(
      x + t*28, 784, nullptr, 0, 32, nullptr, 0, 0,
      h0bf + (s & 1)*PP, FP(OFF_H0F32), h0bf + ((s & 1) ^ 1)*PP,
      y0b + t*512, 28ll*512,
      US(OFF_WCAT0) + 1536ll*576, 576, 18, 1, s == 0,
      FP(OFF_BRZ0) + 1024, FP(OFF_BNIH0) + 512, FP(OFF_BNHH0) + 512);
  }

  // ---- phase B: layer-0 forward + layer-1 forward interleaved ----
  for (int s = 0; s < 28; ++s){
    gru_step_kernel<<<512, 512, 0, stream>>>(
      x + s*28, 784, nullptr, 0, 32, nullptr, 0, 0,
      h0bf + (s & 1)*PP, FP(OFF_H0F32), h0bf + ((s & 1) ^ 1)*PP,
      nullptr, 0,
      US(OFF_WCAT0), 576, 18, 1, s == 0,
      FP(OFF_BRZ0), FP(OFF_BNIH0), FP(OFF_BNHH0));

    gru_step_kernel<<<512, 512, 0, stream>>>(
      nullptr, 0,
      h0bf + ((s & 1) ^ 1)*PP, 512, 512,      // y0f slice = h0f output of this step
      y0b + s*512, 28ll*512, 512,             // y0b slice
      h1bf + (s & 1)*PP, FP(OFF_H1F32), h1bf + ((s & 1) ^ 1)*PP,
      nullptr, 0,
      US(OFF_WCAT1), 1536, 48, 32, s == 0,
      FP(OFF_BRZ1), FP(OFF_BNIH1), FP(OFF_BNHH1));
  }

  // ---- layer-1 backward: single step from h=0 on [y0f(27)|y0b(27)] ----
  gru_step_kernel<<<512, 512, 0, stream>>>(
    nullptr, 0,
    h0bf + 0*PP, 512, 512,                    // y0f t=27 (l0f(27) wrote pp buffer 0)
    y0b + 27*512, 28ll*512, 512,
    h1bf, FP(OFF_H1F32), US(OFF_H1BBF),
    nullptr, 0,
    US(OFF_W1R), 1024, 32, 32, 1,
    FP(OFF_BRZ1R), FP(OFF_BNIH1R), FP(OFF_BNHH1R));

  // ---- head (final h1f is pp buffer 0 after 28 steps) ----
  head_kernel<<<128, 512, 0, stream>>>(
    h1bf, US(OFF_H1BBF), US(OFF_FC1W), US(OFF_FC2W),
    FP(OFF_SC2), FP(OFF_SH2), FP(OFF_FC2B), (float*)d_out);
}